// Round 7
// baseline (102.916 us; speedup 1.0000x reference)
//
#include <hip/hip_runtime.h>

// B=4, IN_C=64, IN_S=16384, OUT_C=64, OUT_S=4096, K=4.
// out[b,o,s] = bias[o,s] + sum_{i,k} x[b,i,4s+k] * w[i,k,o,s]
//
// R7 = R6 with the w base-pointer fix: i-stride is 4*64*4096 = 1048576 elems
// (R6 computed i0*262144 -> ih=1 blocks read the wrong weights).
//
//   thread = (s, o0..o0+3, b=0..3) -> 16 accumulators
//   block  = 256 threads = one s-tile(256 s) x one o-quad x one i-half
//   grid   = 16 s-tiles x 16 o-quads x 2 i-halves = 512 blocks (8 waves/CU)
// - w: dword/lane, lane<->s coalesced, each element read ONCE per grid.
// - x: float4/lane, logical readers per element = 16 o-quads (was 32 o-pairs).
// - i-split 2: partial sums land via unsafeAtomicAdd; out pre-filled with bias.

__global__ __launch_bounds__(256) void bias_init_kernel(
    const float* __restrict__ bias, float* __restrict__ out) {
  int t = blockIdx.x * 256 + threadIdx.x;          // 0..262143 float4 ids
  float4 bv = reinterpret_cast<const float4*>(bias)[t & 65535];
  reinterpret_cast<float4*>(out)[t] = bv;
}

__global__ __launch_bounds__(256) void adj1d_acc_kernel(
    const float* __restrict__ x, const float* __restrict__ w,
    float* __restrict__ out) {

  int bid = blockIdx.x;                 // 0..511
  // XCD swizzle: XCD = bid&7 gets 64 consecutive logical blocks
  // (= 2 s-tiles x 16 o-quads x 2 i-halves) -> x slice ~2.1 MB L2-resident.
  int wgid = (bid & 7) * 64 + (bid >> 3);
  int ih = wgid & 1;                    // i-half
  int oq = (wgid >> 1) & 15;            // o-quad
  int st = wgid >> 5;                   // s-tile (256 s)
  int s  = (st << 8) + threadIdx.x;
  int o0 = oq << 2;
  int i0 = ih << 5;

  float acc[4][4];                      // [o][b]
  #pragma unroll
  for (int o = 0; o < 4; ++o)
    #pragma unroll
    for (int b = 0; b < 4; ++b) acc[o][b] = 0.f;

  const float4* __restrict__ xv = reinterpret_cast<const float4*>(x);
  // w index: ((i*4+k)*64 + o)*4096 + s; strides: i->1048576, k->1<<18, o->1<<12
  const float* __restrict__ wp = w + (size_t)i0 * 1048576 + (o0 << 12) + s;

  #pragma unroll 2
  for (int ii = 0; ii < 32; ++ii) {
    int i = i0 + ii;
    // x: 4 float4 loads (one per batch)
    float4 xa4[4];
    #pragma unroll
    for (int b = 0; b < 4; ++b)
      xa4[b] = xv[(((b << 6) + i) << 12) + s];

    // w: 16 dword loads (4 k x 4 o), batched
    float wv[4][4];                     // [k][o]
    #pragma unroll
    for (int k = 0; k < 4; ++k)
      #pragma unroll
      for (int o = 0; o < 4; ++o)
        wv[k][o] = wp[(k << 18) + (o << 12)];

    float xk[4][4];                     // [b][k]
    #pragma unroll
    for (int b = 0; b < 4; ++b) {
      xk[b][0] = xa4[b].x; xk[b][1] = xa4[b].y;
      xk[b][2] = xa4[b].z; xk[b][3] = xa4[b].w;
    }

    #pragma unroll
    for (int k = 0; k < 4; ++k)
      #pragma unroll
      for (int o = 0; o < 4; ++o)
        #pragma unroll
        for (int b = 0; b < 4; ++b)
          acc[o][b] = fmaf(xk[b][k], wv[k][o], acc[o][b]);

    wp += 1048576;                      // next i
  }

  #pragma unroll
  for (int o = 0; o < 4; ++o)
    #pragma unroll
    for (int b = 0; b < 4; ++b)
      unsafeAtomicAdd(&out[(((b << 6) + o0 + o) << 12) + s], acc[o][b]);
}

extern "C" void kernel_launch(void* const* d_in, const int* in_sizes, int n_in,
                              void* d_out, int out_size, void* d_ws, size_t ws_size,
                              hipStream_t stream) {
  const float* x    = (const float*)d_in[0];  // (4, 64, 16384)
  const float* w    = (const float*)d_in[1];  // (64, 4, 64, 4096)
  const float* bias = (const float*)d_in[2];  // (64, 4096)
  float* out = (float*)d_out;                 // (4, 64, 4096)

  bias_init_kernel<<<1024, 256, 0, stream>>>(bias, out);
  // 16 s-tiles x 16 o-quads x 2 i-halves = 512 blocks
  adj1d_acc_kernel<<<512, 256, 0, stream>>>(x, w, out);
}

// Round 8
// 92.551 us; speedup vs baseline: 1.1120x; 1.1120x over previous
//
#include <hip/hip_runtime.h>

// B=4, IN_C=64, IN_S=16384, OUT_C=64, OUT_S=4096, K=4.
// out[b,o,s] = bias[o,s] + sum_{i,k} x[b,i,4s+k] * w[i,k,o,s]
//
// R8: widen the w stream, shrink stream count, constant occupancy.
//   thread = (2 consecutive s, 1 o, b=0..3) -> 8 accumulators (float2[4])
//   block  = 256 threads = one o x 512-s tile
//   grid   = 8 s-tiles x 64 o = 512 blocks (2/CU, 8 waves/CU — same as R1)
// - w: dwordx2/lane, wave reads 512B contiguous per k -> 4 streams/iter
//   (R1: 8 streams of 256B). Each w element still read ONCE per grid.
// - x: 2 float4/lane per (b,i) -> wave reads 2KB contiguous.
// - XCD swizzle: chunk of 64 wgids = one 512-s tile x all 64 o per XCD ->
//   x slice 2MB L2-resident, all 64 reader blocks co-resident on that XCD.

__global__ __launch_bounds__(256) void adj1d_kernel(
    const float* __restrict__ x, const float* __restrict__ w,
    const float* __restrict__ bias, float* __restrict__ out) {

  int bid = blockIdx.x;                  // 0..511
  int wgid = (bid & 7) * 64 + (bid >> 3);
  int o  = wgid & 63;                    // output channel
  int st = wgid >> 6;                    // s-tile (512 s)
  int s0 = (st << 9) + (threadIdx.x << 1);  // first of this thread's 2 s

  float2 acc[4];                         // [b] = {s0, s0+1}
  #pragma unroll
  for (int b = 0; b < 4; ++b) acc[b] = make_float2(0.f, 0.f);

  const float4* __restrict__ xv = reinterpret_cast<const float4*>(x);
  // x float4 index for (b,i,s): ((b*64+i) << 12) + s   (float4 s = elems 4s..4s+3)
  // w element index: (i*4+k)*262144 + (o<<12) + s ; float2 at even s
  const float* __restrict__ wp0 = w + (o << 12) + s0;

  #pragma unroll 2
  for (int i = 0; i < 64; ++i) {
    // x: 8 consecutive floats per b (elems 4*s0 .. 4*s0+7)
    float4 xa[4][2];
    #pragma unroll
    for (int b = 0; b < 4; ++b) {
      int base = (((b << 6) + i) << 12) + s0;
      xa[b][0] = xv[base];
      xa[b][1] = xv[base + 1];
    }
    // w: 4 float2 loads (one per k), 512B contiguous per wave
    float2 wv[4];
    const float* wp = wp0 + (size_t)i * 1048576;
    #pragma unroll
    for (int k = 0; k < 4; ++k)
      wv[k] = *reinterpret_cast<const float2*>(wp + (k << 18));

    #pragma unroll
    for (int b = 0; b < 4; ++b) {
      const float xs0[4] = {xa[b][0].x, xa[b][0].y, xa[b][0].z, xa[b][0].w};
      const float xs1[4] = {xa[b][1].x, xa[b][1].y, xa[b][1].z, xa[b][1].w};
      #pragma unroll
      for (int k = 0; k < 4; ++k) {
        acc[b].x = fmaf(xs0[k], wv[k].x, acc[b].x);
        acc[b].y = fmaf(xs1[k], wv[k].y, acc[b].y);
      }
    }
  }

  float2 bv = *reinterpret_cast<const float2*>(bias + (o << 12) + s0);
  #pragma unroll
  for (int b = 0; b < 4; ++b) {
    float2 r = make_float2(acc[b].x + bv.x, acc[b].y + bv.y);
    *reinterpret_cast<float2*>(out + (((b << 6) + o) << 12) + s0) = r;
  }
}

extern "C" void kernel_launch(void* const* d_in, const int* in_sizes, int n_in,
                              void* d_out, int out_size, void* d_ws, size_t ws_size,
                              hipStream_t stream) {
  const float* x    = (const float*)d_in[0];  // (4, 64, 16384)
  const float* w    = (const float*)d_in[1];  // (64, 4, 64, 4096)
  const float* bias = (const float*)d_in[2];  // (64, 4096)
  float* out = (float*)d_out;                 // (4, 64, 4096)

  // 8 s-tiles x 64 o = 512 blocks, 256 threads each
  adj1d_kernel<<<512, 256, 0, stream>>>(x, w, bias, out);
}

// Round 9
// 62.779 us; speedup vs baseline: 1.6393x; 1.4742x over previous
//
#include <hip/hip_runtime.h>

// B=4, IN_C=64, IN_S=16384, OUT_C=64, OUT_S=4096, K=4.
// out[b,o,s] = bias[o,s] + sum_{i,k} x[b,i,4s+k] * w[i,k,o,s]
//
// R9: R1's exact per-thread/per-wave microstructure (thread = 1s x 2o x 4b;
// wave = 64 s x one o-pair: 8 w-streams of 256B/iter, 1KB x wave-loads),
// with ONLY the block geometry changed: block = 8 o x 64 s (4 waves = the
// 4 o-pairs of an o-oct over the same 64-s range).
//   - x logical readers per element: 32 -> 8  (x L2 traffic 512 -> 128 MB)
//   - the 4 waves read IDENTICAL x addresses -> L1 serves 3 of 4
//   - w still read exactly once grid-wide, same stream pattern as R1
//   grid = 64 s-tiles x 8 o-octs = 512 blocks (2/CU, 8 waves/CU — same as R1)
// XCD swizzle: 64 consecutive wgids per XCD = 8 s-tiles x all 8 o-octs ->
// per-XCD x slice 2 MB, all readers of a slice co-resident on one XCD.

__global__ __launch_bounds__(256) void adj1d_kernel(
    const float* __restrict__ x, const float* __restrict__ w,
    const float* __restrict__ bias, float* __restrict__ out) {

  int bid = blockIdx.x;                 // 0..511
  int wgid = (bid & 7) * 64 + (bid >> 3);
  int og = wgid & 7;                    // o-oct group (8 output channels)
  int st = wgid >> 3;                   // s-tile (64 s)
  int lane = threadIdx.x & 63;
  int wv   = threadIdx.x >> 6;          // wave id = o-pair within the oct
  int s  = (st << 6) + lane;
  int o0 = (og << 3) + (wv << 1);

  float acc00 = 0.f, acc01 = 0.f, acc02 = 0.f, acc03 = 0.f;  // o0,   b=0..3
  float acc10 = 0.f, acc11 = 0.f, acc12 = 0.f, acc13 = 0.f;  // o0+1, b=0..3

  const float4* __restrict__ xv = reinterpret_cast<const float4*>(x);
  // w element index: ((i*4+k)*64 + o)*4096 + s ; per-(i,k) stride = 262144 elems
  const float* __restrict__ wp0 = w + (o0 << 12) + s;

  #pragma unroll 2
  for (int i = 0; i < 64; ++i) {
    float xa[4][4];  // [b][k]
    *reinterpret_cast<float4*>(xa[0]) = xv[((0 * 64 + i) << 12) + s];
    *reinterpret_cast<float4*>(xa[1]) = xv[((1 * 64 + i) << 12) + s];
    *reinterpret_cast<float4*>(xa[2]) = xv[((2 * 64 + i) << 12) + s];
    *reinterpret_cast<float4*>(xa[3]) = xv[((3 * 64 + i) << 12) + s];
    #pragma unroll
    for (int k = 0; k < 4; ++k) {
      const float* wp = wp0 + (size_t)(i * 4 + k) * 262144;
      float wa = wp[0];
      float wb = wp[4096];
      acc00 = fmaf(xa[0][k], wa, acc00);
      acc01 = fmaf(xa[1][k], wa, acc01);
      acc02 = fmaf(xa[2][k], wa, acc02);
      acc03 = fmaf(xa[3][k], wa, acc03);
      acc10 = fmaf(xa[0][k], wb, acc10);
      acc11 = fmaf(xa[1][k], wb, acc11);
      acc12 = fmaf(xa[2][k], wb, acc12);
      acc13 = fmaf(xa[3][k], wb, acc13);
    }
  }

  float bA = bias[(o0 << 12) + s];
  float bB = bias[((o0 + 1) << 12) + s];

  out[((0 * 64 + o0) << 12) + s]     = acc00 + bA;
  out[((1 * 64 + o0) << 12) + s]     = acc01 + bA;
  out[((2 * 64 + o0) << 12) + s]     = acc02 + bA;
  out[((3 * 64 + o0) << 12) + s]     = acc03 + bA;
  out[((0 * 64 + o0 + 1) << 12) + s] = acc10 + bB;
  out[((1 * 64 + o0 + 1) << 12) + s] = acc11 + bB;
  out[((2 * 64 + o0 + 1) << 12) + s] = acc12 + bB;
  out[((3 * 64 + o0 + 1) << 12) + s] = acc13 + bB;
}

extern "C" void kernel_launch(void* const* d_in, const int* in_sizes, int n_in,
                              void* d_out, int out_size, void* d_ws, size_t ws_size,
                              hipStream_t stream) {
  const float* x    = (const float*)d_in[0];  // (4, 64, 16384)
  const float* w    = (const float*)d_in[1];  // (64, 4, 64, 4096)
  const float* bias = (const float*)d_in[2];  // (64, 4096)
  float* out = (float*)d_out;                 // (4, 64, 4096)

  // 64 s-tiles x 8 o-octs = 512 blocks, 256 threads each
  adj1d_kernel<<<512, 256, 0, stream>>>(x, w, bias, out);
}